// Round 15
// baseline (82.051 us; speedup 1.0000x reference)
//
#include <hip/hip_runtime.h>
#include <hip/hip_bf16.h>

// pointconv: density MLP + weight-net + per-point [64x32]x[32x32] + [128x2048] GEMV + BN
// B=16 NP=1024 NS=32 CIN=64 CMID=32 COUT=128. Inputs f32, outputs f32 (bf16 MFMA inside).
// R15: same 64-pt fused block, restructured for TLP + fewer LDS instrs:
//  - 16 waves (1024 thr): 4 waves/SIMD (was 2) -> 2x latency hiding, per-wave phases halve
//  - weight-net computed in CONSUMER layout (lane l15=k): bfr built in registers,
//    wd LDS round-trip deleted (-32KB LDS, -1 transpose, same FLOPs, bit-identical)
//  - fs staged via 4x ds_write_b128/thread (was 32x b32): 4x fewer LDS write instrs
// LDS = union(gxd 32K, fs 64K) + mm 64K + cst ~= 129 KB, 1 block/CU, 16 waves.

#define NPP 1024

// LDS-ordered barrier WITHOUT vmcnt drain (global loads stay in flight).
#define BARRIER() do {                                          \
  asm volatile("s_waitcnt lgkmcnt(0)" ::: "memory");            \
  __builtin_amdgcn_s_barrier();                                 \
  __builtin_amdgcn_sched_barrier(0);                            \
} while (0)

typedef __attribute__((ext_vector_type(8))) short short8;
typedef __attribute__((ext_vector_type(4))) float f32x4;

__device__ __forceinline__ unsigned short f2bf(float x) {
  union { float f; unsigned u; } v; v.f = x;
  unsigned r = v.u + 0x7FFFu + ((v.u >> 16) & 1u);   // RNE
  return (unsigned short)(r >> 16);
}

__device__ __forceinline__ unsigned long long pack4bf(f32x4 v) {
  return (unsigned long long)f2bf(v[0])
       | ((unsigned long long)f2bf(v[1]) << 16)
       | ((unsigned long long)f2bf(v[2]) << 32)
       | ((unsigned long long)f2bf(v[3]) << 48);
}

// ---- k_prep: OWc chunk-major bf16 + output-0 transpose (unchanged) ----
__global__ __launch_bounds__(256) void k_prep(
    const float* __restrict__ out_w, const float* __restrict__ new_xyz,
    unsigned short* __restrict__ owc, float* __restrict__ out0)
{
  int bid = blockIdx.x, t = threadIdx.x;
  if (bid < 128) {
    int gid = bid * 256 + t;           // 32768 = 512 chunks x 64 lanes
    int lane = gid & 63, ci = gid >> 6;
    int hi = ci & 1, tt = (ci >> 1) & 15, cblk = (ci >> 5) & 3, w = ci >> 7;
    int sg = lane >> 4, l15 = lane & 15;
    int o = w*32 + hi*16 + l15;
    int k = tt*2 + (sg >> 1);
    int cbase = cblk*16 + (sg & 1)*8;
    short8 vv;
    #pragma unroll
    for (int j = 0; j < 8; ++j)
      vv[j] = (short)f2bf(out_w[(o*64 + cbase + j)*32 + k]);
    *(short8*)&owc[(size_t)gid * 8] = vv;
  } else {
    int idx = (bid - 128) * 256 + t;   // < 49152
    int b = idx / 3072, r = idx - b*3072, p = r / 3, d = r - p*3;
    out0[idx] = new_xyz[(b*3 + d)*NPP + p];
  }
}

// ---- k_main v5: one wg = (b, 64-point tile), 16 waves (1024 thr) ----
struct Smem5 {
  union {
    float gxd[64*32*4];          // (x,y,z,d2) per (p,s)   32 KB  (phase 0)
    unsigned short fs[32768];    // per-cblk F tile swizz  64 KB  (main loop)
  } u;
  char mm[64*1024];              // [p][kflat-this-cblk] swizz  64 KB
  float cst[192];
};

__global__ __launch_bounds__(1024) void k_main(
    const float* __restrict__ F, const float* __restrict__ GX,
    const float* __restrict__ whw, const float* __restrict__ whb,
    const float* __restrict__ whg, const float* __restrict__ whbeta,
    const float* __restrict__ whm, const float* __restrict__ whv,
    const float* __restrict__ n1w, const float* __restrict__ n1b,
    const float* __restrict__ n1g, const float* __restrict__ n1beta,
    const float* __restrict__ n1m, const float* __restrict__ n1v,
    const float* __restrict__ n2w, const float* __restrict__ n2b,
    const float* __restrict__ n2g, const float* __restrict__ n2beta,
    const float* __restrict__ n2m, const float* __restrict__ n2v,
    const unsigned short* __restrict__ OWc,
    const float* __restrict__ ob, const float* __restrict__ og,
    const float* __restrict__ obeta, const float* __restrict__ om,
    const float* __restrict__ ov,
    float* __restrict__ out1)
{
  __shared__ Smem5 sm;
  int xcd = blockIdx.x & 7, idx = blockIdx.x >> 3;   // b pinned to XCD
  int b = xcd*2 + (idx >> 4), pt64 = idx & 15;
  int p0 = pt64 * 64;
  int t = threadIdx.x, w = t >> 6, lane = t & 63;
  int l15 = lane & 15, sg = lane >> 4;

  // ---- staging roles: wave -> (so = s-octet, pq = p-quarter); lane -> (q4, c3, jh) ----
  int so = w & 3, pq = w >> 2;
  int q4 = lane & 3, c3 = (lane >> 2) & 7, jh = (lane >> 5) & 1;
  int cw = jh*8 + c3;                  // c within the cblk's 16
  const float* fsrc0 = &F[((size_t)((b*64 + cw)*32) + so*8)*NPP + p0 + pq*16 + q4*4];

  // ---- issue cblk0 F loads (8 float4/thread, hidden under phase 0) ----
  float4 fv[8];
  #pragma unroll
  for (int jj = 0; jj < 8; ++jj)
    fv[jj] = *(const float4*)&fsrc0[(size_t)jj*NPP];

  // ---- phase 0a loads: gx (threads 0..511) ----
  float4 f0, f1, f2;
  int pp8 = t >> 3, si8 = t & 7;
  if (t < 512) {
    const float* g = &GX[(size_t)(b*NPP + p0 + pp8)*96 + si8*12];
    f0 = *(const float4*)g;
    f1 = *(const float4*)(g + 4);
    f2 = *(const float4*)(g + 8);
  }

  // folded BN consts
  if (t < 32) {
    float sc = whg[t] * rsqrtf(whv[t] + 1e-5f);
    sm.cst[t]    = whw[t*3+0] * sc;
    sm.cst[32+t] = whw[t*3+1] * sc;
    sm.cst[64+t] = whw[t*3+2] * sc;
    sm.cst[96+t] = (whb[t] - whm[t]) * sc + whbeta[t];
  } else if (t < 48) {
    int i = t - 32;
    float sc = n1g[i] * rsqrtf(n1v[i] + 1e-5f);
    sm.cst[128+i] = n1w[i] * sc;
    sm.cst[144+i] = (n1b[i] - n1m[i]) * sc + n1beta[i];
  } else if (t < 64) {
    int i = t - 48;
    float sc = n2g[0] * rsqrtf(n2v[0] + 1e-5f);
    sm.cst[160+i] = n2w[i] * sc;
    if (i == 0) sm.cst[176] = (n2b[0] - n2m[0]) * sc + n2beta[0];
  }
  __syncthreads();

  // ---- phase 0a compute: density, d2 -> gxd (threads 0..511) ----
  if (t < 512) {
    float xs[4], ys[4], zs[4], inv[4];
    xs[0]=f0.x; ys[0]=f0.y; zs[0]=f0.z;
    xs[1]=f0.w; ys[1]=f1.x; zs[1]=f1.y;
    xs[2]=f1.z; ys[2]=f1.w; zs[2]=f2.x;
    xs[3]=f2.y; ys[3]=f2.z; zs[3]=f2.w;
    if (si8 == 0) { xs[0]=0.f; ys[0]=0.f; zs[0]=0.f; }   // s=0 zeroed per reference
    float mx = 0.f;
    #pragma unroll
    for (int u = 0; u < 4; ++u) {
      float den = xs[u] + ys[u] + zs[u];
      if (den < 1e-10f) den = 1e-10f;
      inv[u] = 1.0f / den;
      mx = fmaxf(mx, inv[u]);
    }
    #pragma unroll
    for (int m = 1; m < 8; m <<= 1) mx = fmaxf(mx, __shfl_xor(mx, m, 8));
    #pragma unroll
    for (int u = 0; u < 4; ++u) {
      float ds = inv[u] / mx;
      float acc = sm.cst[176];
      #pragma unroll
      for (int i = 0; i < 16; ++i) {
        float d1 = fmaxf(ds * sm.cst[128+i] + sm.cst[144+i], 0.f);
        acc += d1 * sm.cst[160+i];
      }
      float d2 = 1.0f / (1.0f + expf(-acc));
      float4 st = {xs[u], ys[u], zs[u], d2};
      *(float4*)&sm.u.gxd[(size_t)(pp8*32 + si8*4 + u)*4] = st;
    }
  }
  __syncthreads();

  // ---- phase 0b: weight-net in CONSUMER layout, bfr built in registers ----
  // wave w owns points pt = (pi>>1)*32 + w*2 + (pi&1), pi = 0..3.
  // lane (l15, sg): k = kh*16 + l15, s = sg*8 + j  -> each (pt,k,s) computed once.
  const f32x4 z4 = {0,0,0,0};
  int c0 = l15*32 + sg*8;
  short8 bfr[4][2];
  #pragma unroll
  for (int pi = 0; pi < 4; ++pi) {
    int pt = (pi >> 1)*32 + w*2 + (pi & 1);
    float4 gr[8];
    #pragma unroll
    for (int j = 0; j < 8; ++j)
      gr[j] = *(const float4*)&sm.u.gxd[(size_t)(pt*32 + sg*8 + j)*4];
    #pragma unroll
    for (int kh = 0; kh < 2; ++kh) {
      int k = kh*16 + l15;
      float a0 = sm.cst[k], a1 = sm.cst[32+k], a2 = sm.cst[64+k], bc = sm.cst[96+k];
      short8 v;
      #pragma unroll
      for (int j = 0; j < 8; ++j) {
        float wv = fmaxf(gr[j].x*a0 + gr[j].y*a1 + gr[j].z*a2 + bc, 0.f) * gr[j].w;
        v[j] = (short)f2bf(wv);
      }
      bfr[pi][kh] = v;
    }
  }
  BARRIER();   // gxd dead; fs may overwrite

  // ---- main loop: per cblk: {fs b128-write; issue next F; BAR; stage1; BAR; stage2; BAR} ----
  int w4 = w & 3, gp = w >> 2;
  f32x4 acc0 = {0,0,0,0}, acc1 = {0,0,0,0};
  int rowG = gp*16 + l15;
  unsigned swG = (unsigned)(rowG & 15) << 4;
  const char* bbase = sm.mm + rowG*1024;
  int fsb = so*128 + cw*8;             // u16 idx base (+ p*512, ^ (p&15)<<3)

  #pragma unroll
  for (int cblk = 0; cblk < 4; ++cblk) {
    // fs staging: 4 x ds_write_b128 (8 s-values per point)
    #pragma unroll
    for (int pi = 0; pi < 4; ++pi) {
      int p = pq*16 + q4*4 + pi;
      short8 vv;
      #pragma unroll
      for (int jj = 0; jj < 8; ++jj)
        vv[jj] = (short)f2bf(((const float*)&fv[jj])[pi]);
      unsigned fi = ((unsigned)(p*512 + fsb)) ^ ((unsigned)(p & 15) << 3);
      *(short8*)&sm.u.fs[fi] = vv;
    }
    // issue next cblk's F loads (in flight across the raw barriers)
    if (cblk < 3) {
      const float* fsrc = fsrc0 + (size_t)(cblk + 1) * 16 * 32 * NPP;
      #pragma unroll
      for (int jj = 0; jj < 8; ++jj)
        fv[jj] = *(const float4*)&fsrc[(size_t)jj*NPP];
    }
    BARRIER();

    // stage 1: af from fs (b128, 1KB-dense), MFMA -> mm (XOR-swizzled rows)
    #pragma unroll
    for (int pi = 0; pi < 4; ++pi) {
      int pt = (pi >> 1)*32 + w*2 + (pi & 1);
      unsigned ia = ((unsigned)(pt*512 + sg*128 + l15*8)) ^ ((unsigned)(pt & 15) << 3);
      short8 af = *(const short8*)&sm.u.fs[ia];
      f32x4 m0 = __builtin_amdgcn_mfma_f32_16x16x32_bf16(af, bfr[pi][0], z4, 0,0,0);
      f32x4 m1 = __builtin_amdgcn_mfma_f32_16x16x32_bf16(af, bfr[pi][1], z4, 0,0,0);
      unsigned swr = (unsigned)(pt & 15) << 4;
      char* bA = sm.mm + pt*1024;
      *(unsigned long long*)(bA + ((c0      ) ^ swr)) = pack4bf(m0);
      *(unsigned long long*)(bA + ((c0 + 512) ^ swr)) = pack4bf(m1);
    }
    BARRIER();

    // stage 2: OWc x mm, accumulate
    {
      const unsigned short* ac = &OWc[(size_t)((w4*4 + cblk)*16)*1024 + lane*8];
      #pragma unroll 8
      for (int tt = 0; tt < 16; ++tt) {
        short8 a0 = *(const short8*)&ac[tt*1024];
        short8 a1 = *(const short8*)&ac[tt*1024 + 512];
        int col = sg*16 + tt*64;
        short8 bb = *(const short8*)(bbase + (col ^ swG));
        acc0 = __builtin_amdgcn_mfma_f32_16x16x32_bf16(a0, bb, acc0, 0,0,0);
        acc1 = __builtin_amdgcn_mfma_f32_16x16x32_bf16(a1, bb, acc1, 0,0,0);
      }
    }
    BARRIER();
  }

  // ---- epilogue: +bias, BN, f32 store ----
  #pragma unroll
  for (int hi = 0; hi < 2; ++hi) {
    f32x4 a = hi ? acc1 : acc0;
    #pragma unroll
    for (int r = 0; r < 4; ++r) {
      int o = w4*32 + hi*16 + sg*4 + r;
      float sc = og[o] * rsqrtf(ov[o] + 1e-5f);
      float dd = (ob[o] - om[o]) * sc + obeta[o];
      out1[(size_t)(b*128 + o)*NPP + p0 + gp*16 + l15] = a[r] * sc + dd;
    }
  }
}

extern "C" void kernel_launch(void* const* d_in, const int* in_sizes, int n_in,
                              void* d_out, int out_size, void* d_ws, size_t ws_size,
                              hipStream_t stream) {
  (void)in_sizes; (void)n_in; (void)out_size; (void)ws_size;
  const float* new_xyz = (const float*)d_in[0];
  const float* gxyz    = (const float*)d_in[1];
  const float* gfeat   = (const float*)d_in[2];
  const float* whw     = (const float*)d_in[3];
  const float* whb     = (const float*)d_in[4];
  const float* whg     = (const float*)d_in[5];
  const float* whbeta  = (const float*)d_in[6];
  const float* whm     = (const float*)d_in[7];
  const float* whv     = (const float*)d_in[8];
  const float* n1w     = (const float*)d_in[9];
  const float* n1b     = (const float*)d_in[10];
  const float* n1g     = (const float*)d_in[11];
  const float* n1beta  = (const float*)d_in[12];
  const float* n1m     = (const float*)d_in[13];
  const float* n1v     = (const float*)d_in[14];
  const float* n2w     = (const float*)d_in[15];
  const float* n2b     = (const float*)d_in[16];
  const float* n2g     = (const float*)d_in[17];
  const float* n2beta  = (const float*)d_in[18];
  const float* n2m     = (const float*)d_in[19];
  const float* n2v     = (const float*)d_in[20];
  const float* out_w   = (const float*)d_in[21];
  const float* out_b   = (const float*)d_in[22];
  const float* out_g   = (const float*)d_in[23];
  const float* out_bt  = (const float*)d_in[24];
  const float* out_m   = (const float*)d_in[25];
  const float* out_v   = (const float*)d_in[26];

  unsigned short* owc = (unsigned short*)d_ws;   // 512 KB chunk-major weights
  float* out0 = (float*)d_out;                   // [16][1024][3] f32
  float* out1 = out0 + 16*1024*3;                // [16][128][1024] f32

  hipLaunchKernelGGL(k_prep, dim3(320), dim3(256), 0, stream, out_w, new_xyz, owc, out0);
  hipLaunchKernelGGL(k_main, dim3(256), dim3(1024), 0, stream,
      gfeat, gxyz, whw, whb, whg, whbeta, whm, whv,
      n1w, n1b, n1g, n1beta, n1m, n1v,
      n2w, n2b, n2g, n2beta, n2m, n2v,
      owc, out_b, out_g, out_bt, out_m, out_v, out1);
}